// Round 11
// baseline (709.508 us; speedup 1.0000x reference)
//
#include <hip/hip_runtime.h>
#include <hip/hip_bf16.h>
#include <cstdint>
#include <cstddef>

#define BATCH 8192
#define INSZ 4096
#define HID 4096
#define NCLS 10

typedef float f32x4 __attribute__((ext_vector_type(4)));
typedef int i32x4 __attribute__((ext_vector_type(4)));
typedef char i8x16 __attribute__((ext_vector_type(16)));

__device__ __forceinline__ void async_copy16(const void* g, void* l) {
  __builtin_amdgcn_global_load_lds(
      (const __attribute__((address_space(1))) void*)g,
      (__attribute__((address_space(3))) void*)l, 16, 0, 0);
}

// ---------------------------------------------------------------------------
// One fused sign-cast pass for ALL inputs: f32 -> i8 in {-1,0,+1}.
// ---------------------------------------------------------------------------
__global__ __launch_bounds__(256)
void sign_cast_all(const float* __restrict__ x, const float* __restrict__ W0,
                   const float* __restrict__ W1, const float* __restrict__ W2,
                   const float* __restrict__ W3,
                   int8_t* __restrict__ actA, int8_t* __restrict__ wb0,
                   int8_t* __restrict__ wb1, int8_t* __restrict__ wb2,
                   int8_t* __restrict__ w3b) {
  constexpr int CX = 2097152;           // 8192*4096/16
  constexpr int CW = 1048576;           // 4096*4096/16
  const int c = blockIdx.x * blockDim.x + threadIdx.x;

  const float* src;
  int8_t* dst;
  int base;
  if (c < CX)               { src = x;  dst = actA; base = c; }
  else if (c < CX + CW)     { src = W0; dst = wb0;  base = c - CX; }
  else if (c < CX + 2 * CW) { src = W1; dst = wb1;  base = c - (CX + CW); }
  else if (c < CX + 3 * CW) { src = W2; dst = wb2;  base = c - (CX + 2 * CW); }
  else                      { src = W3; dst = w3b;  base = c - (CX + 3 * CW); }

  const f32x4* in4 = (const f32x4*)src + (size_t)base * 4;
  i8x16 s;
#pragma unroll
  for (int q = 0; q < 4; ++q) {
    f32x4 v = in4[q];
#pragma unroll
    for (int j = 0; j < 4; ++j) s[q * 4 + j] = (char)((v[j] > 0.f) - (v[j] < 0.f));
  }
  ((i8x16*)dst)[base] = s;
}

// ---------------------------------------------------------------------------
// 256x256 8-phase i8 GEMM: C = sign(A @ B^T).
// Round-10 change vs verified round-5 kernel: hold BOTH B halves in registers
// for the whole K-tile (loaded once in p1). ds_read_b128 per K-tile per wave
// drops 28 -> 24 (the unique-byte floor); p2/p4 have no LDS reads; the p4
// B0 re-read is gone. Staging/vmcnt schedule unchanged (hazards only relax:
// B LDS regions are free after p1's reads).
// ---------------------------------------------------------------------------

#define MMA_QUAD(QM, QN)                                                      \
  do {                                                                        \
    _Pragma("unroll") for (int m4 = 0; m4 < 4; ++m4) {                        \
      _Pragma("unroll") for (int n2 = 0; n2 < 2; ++n2) {                      \
        acc[(QM)*4 + m4][(QN)*2 + n2] = __builtin_amdgcn_mfma_i32_16x16x64_i8( \
            af[m4][0], bfr[QN][n2][0], acc[(QM)*4 + m4][(QN)*2 + n2], 0, 0, 0); \
        acc[(QM)*4 + m4][(QN)*2 + n2] = __builtin_amdgcn_mfma_i32_16x16x64_i8( \
            af[m4][1], bfr[QN][n2][1], acc[(QM)*4 + m4][(QN)*2 + n2], 0, 0, 0); \
      }                                                                       \
    }                                                                         \
  } while (0)

#define LDA_HALF(BUFA)                                                        \
  do {                                                                        \
    _Pragma("unroll") for (int m4 = 0; m4 < 4; ++m4) {                        \
      af[m4][0] = *(const i32x4*)((BUFA) + m4 * 4096 + aRowB + c0);           \
      af[m4][1] = *(const i32x4*)((BUFA) + m4 * 4096 + aRowB + c1);           \
    }                                                                         \
  } while (0)

// Load BOTH B halves (8 x ds_read_b128) for the whole K-tile.
#define LDB_ALL(BUFC)                                                         \
  do {                                                                        \
    _Pragma("unroll") for (int h = 0; h < 2; ++h) {                           \
      _Pragma("unroll") for (int n2 = 0; n2 < 2; ++n2) {                      \
        bfr[h][n2][0] =                                                       \
            *(const i32x4*)((BUFC) + 32768 + h * 16384 + n2 * 8192 + bRowB + c0); \
        bfr[h][n2][1] =                                                       \
            *(const i32x4*)((BUFC) + 32768 + h * 16384 + n2 * 8192 + bRowB + c1); \
      }                                                                       \
    }                                                                         \
  } while (0)

#define STAGE(GBASE, LHALF, TCOL)                                             \
  do {                                                                        \
    async_copy16((GBASE) + (TCOL), (LHALF) + dst0);                           \
    async_copy16((GBASE) + jstride + (TCOL), (LHALF) + dst0 + 8192);          \
  } while (0)

#define BAR() __builtin_amdgcn_s_barrier()

__global__ __launch_bounds__(512, 2)
void gemm256_i8_sign(const int8_t* __restrict__ A, const int8_t* __restrict__ B,
                     int8_t* __restrict__ C, int M, int N, int K) {
  constexpr int BM = 256, BN = 256, BK = 128;
  constexpr int NXCD = 8;
  __shared__ char lds[2][65536];

  const int nbn = N / BN;
  const int nwg = gridDim.x;
  const int cpx = nwg / NXCD;
  const int bid = (blockIdx.x % NXCD) * cpx + blockIdx.x / NXCD;
  const int bm = bid / nbn, bn = bid % nbn;

  const int tid = threadIdx.x;
  const int lane = tid & 63;
  const int w = tid >> 6;
  const int wr = w >> 2;
  const int wc = w & 3;

  const int src16 = lane ^ (lane >> 3);
  const int srow0 = w * 8 + (src16 >> 3);
  const int scol  = (src16 & 7) * 16;
  const int8_t* aBase0 = A + (size_t)(bm * BM + srow0) * K + scol;
  const int8_t* aBase1 = A + (size_t)(bm * BM + 128 + srow0) * K + scol;
  const int8_t* bBase0 = B + (size_t)(bn * BN + srow0) * K + scol;
  const int8_t* bBase1 = B + (size_t)(bn * BN + 128 + srow0) * K + scol;
  const size_t jstride = (size_t)64 * K;
  const int dst0 = w * 1024 + lane * 16;

  const int rf = lane & 15;
  const int c0 = ((lane >> 4) * 16) ^ ((lane & 7) << 4);
  const int c1 = (64 + (lane >> 4) * 16) ^ ((lane & 7) << 4);
  const int aRowB = (wr * 16 + rf) * 128;
  const int bRowB = (wc * 16 + rf) * 128;

  i32x4 acc[8][4];
#pragma unroll
  for (int m = 0; m < 8; ++m)
#pragma unroll
    for (int n = 0; n < 4; ++n) acc[m][n] = (i32x4){0, 0, 0, 0};

  i32x4 af[4][2];
  i32x4 bfr[2][2][2];   // [N-half][n2][kstep] — whole K-tile's B in regs

  const int NT = K / BK;

  STAGE(aBase0, lds[0] + 0,     0);
  STAGE(bBase0, lds[0] + 32768, 0);
  STAGE(bBase1, lds[0] + 49152, 0);
  STAGE(aBase1, lds[0] + 16384, 0);
  STAGE(aBase0, lds[1] + 0,     BK);
  STAGE(bBase1, lds[1] + 49152, BK);
  asm volatile("s_waitcnt vmcnt(4)" ::: "memory");
  BAR();

  for (int k = 0; k < NT; ++k) {
    char* bufc = lds[k & 1];
    char* bufo = lds[(k & 1) ^ 1];
    const int t1 = (k + 1) * BK, t2 = (k + 2) * BK;
    const bool s1 = (k + 1 < NT), s2 = (k + 2 < NT);

    // ---- p1: quadrant (0,0); read A-half0 + ALL of B ----
    LDA_HALF(bufc + 0);
    LDB_ALL(bufc);
    if (s1) STAGE(bBase0, bufo + 32768, t1);
    BAR();
    __builtin_amdgcn_s_setprio(1);
    MMA_QUAD(0, 0);
    __builtin_amdgcn_s_setprio(0);
    BAR();

    // ---- p2: quadrant (0,1); no LDS reads ----
    if (s1) STAGE(aBase1, bufo + 16384, t1);
    BAR();
    __builtin_amdgcn_s_setprio(1);
    MMA_QUAD(0, 1);
    __builtin_amdgcn_s_setprio(0);
    BAR();

    // ---- p3: quadrant (1,1); read A-half1 ----
    LDA_HALF(bufc + 16384);
    if (s2) STAGE(aBase0, bufc + 0, t2);
    BAR();
    __builtin_amdgcn_s_setprio(1);
    MMA_QUAD(1, 1);
    __builtin_amdgcn_s_setprio(0);
    BAR();

    // ---- p4: quadrant (1,0); no LDS reads ----
    if (s2) STAGE(bBase1, bufc + 49152, t2);
    BAR();
    __builtin_amdgcn_s_setprio(1);
    MMA_QUAD(1, 0);
    __builtin_amdgcn_s_setprio(0);
    if (k < NT - 1) {
      if (k <= NT - 3)
        asm volatile("s_waitcnt vmcnt(4)" ::: "memory");
      else
        asm volatile("s_waitcnt vmcnt(0)" ::: "memory");
    }
    BAR();
  }

  const int ch = lane >> 4;
#pragma unroll
  for (int m = 0; m < 8; ++m) {
    const int qm = m >> 2, m4 = m & 3;
#pragma unroll
    for (int n = 0; n < 4; ++n) {
      const int qn = n >> 1, n2 = n & 1;
#pragma unroll
      for (int r = 0; r < 4; ++r) {
        int v = acc[m][n][r];
        C[(size_t)(bm * BM + qm * 128 + m4 * 32 + wr * 16 + ch * 4 + r) * N +
          (bn * BN + qn * 128 + n2 * 64 + wc * 16 + rf)] = (int8_t)((v > 0) - (v < 0));
      }
    }
  }
}

// Last layer: [8192x4096] i8 x [10x4096] i8^T -> sign -> [8192x10] f32.
typedef char i8x16v __attribute__((ext_vector_type(16)));
__global__ __launch_bounds__(256)
void final_layer_i8(const int8_t* __restrict__ A, const int8_t* __restrict__ W,
                    float* __restrict__ out) {
  const int lane = threadIdx.x & 63;
  const int wave = threadIdx.x >> 6;
  const int row = blockIdx.x * 4 + wave;
  const int8_t* a = A + (size_t)row * HID;

  int acc[NCLS];
#pragma unroll
  for (int n = 0; n < NCLS; ++n) acc[n] = 0;

#pragma unroll
  for (int c = 0; c < HID / 1024; ++c) {
    const int k = c * 1024 + lane * 16;
    i8x16v av = *(const i8x16v*)(a + k);
#pragma unroll
    for (int n = 0; n < NCLS; ++n) {
      i8x16v wv = *(const i8x16v*)(W + (size_t)n * HID + k);
      int s = 0;
#pragma unroll
      for (int j = 0; j < 16; ++j) s += (int)av[j] * (int)wv[j];
      acc[n] += s;
    }
  }

#pragma unroll
  for (int n = 0; n < NCLS; ++n) {
    int v = acc[n];
#pragma unroll
    for (int off = 32; off > 0; off >>= 1) v += __shfl_xor(v, off, 64);
    if (lane == 0) out[(size_t)row * NCLS + n] = (float)((v > 0) - (v < 0));
  }
}

extern "C" void kernel_launch(void* const* d_in, const int* in_sizes, int n_in,
                              void* d_out, int out_size, void* d_ws, size_t ws_size,
                              hipStream_t stream) {
  const float* x  = (const float*)d_in[0];
  const float* W0 = (const float*)d_in[1];
  const float* W1 = (const float*)d_in[2];
  const float* W2 = (const float*)d_in[3];
  const float* W3 = (const float*)d_in[4];
  float* out = (float*)d_out;

  // Workspace (~112 MiB): actA 32M | actB 32M | wbuf0/1/2 16M each | w3buf 40K
  char* ws = (char*)d_ws;
  int8_t* actA  = (int8_t*)ws;
  int8_t* actB  = (int8_t*)(ws + (size_t)BATCH * HID);
  int8_t* wb0   = (int8_t*)(ws + (size_t)2 * BATCH * HID);
  int8_t* wb1   = (int8_t*)(ws + (size_t)2 * BATCH * HID + (size_t)HID * HID);
  int8_t* wb2   = (int8_t*)(ws + (size_t)2 * BATCH * HID + (size_t)2 * HID * HID);
  int8_t* w3buf = (int8_t*)(ws + (size_t)2 * BATCH * HID + (size_t)3 * HID * HID);

  const int gemm_grid = (BATCH / 256) * (HID / 256);  // 512, % 8 == 0

  const int total_chunks = 2097152 + 3 * 1048576 + 2560;
  sign_cast_all<<<total_chunks / 256, dim3(256), 0, stream>>>(
      x, W0, W1, W2, W3, actA, wb0, wb1, wb2, w3buf);

  gemm256_i8_sign<<<gemm_grid, dim3(512), 0, stream>>>(actA, wb0, actB, BATCH, HID, INSZ);
  gemm256_i8_sign<<<gemm_grid, dim3(512), 0, stream>>>(actB, wb1, actA, BATCH, HID, HID);
  gemm256_i8_sign<<<gemm_grid, dim3(512), 0, stream>>>(actA, wb2, actB, BATCH, HID, HID);
  final_layer_i8<<<BATCH / 4, dim3(256), 0, stream>>>(actB, w3buf, out);
}